// Round 8
// baseline (134.525 us; speedup 1.0000x reference)
//
#include <hip/hip_runtime.h>
#include <math.h>

#define BATCH 512

__device__ __forceinline__ float elu1(float v) {
    return v > 0.f ? v : expm1f(v);
}

// ============ Kernel 1: conv1 (9-dir stencil, 1->32) + ELU + 2x2 pool ============
__global__ __launch_bounds__(256) void k1_conv1_pool(
    const float* __restrict__ x, const float* __restrict__ W1,
    const float* __restrict__ root1, const float* __restrict__ b1,
    float* __restrict__ p1) {
    __shared__ float xs[900];            // [30][30] zero-padded image
    __shared__ float w1s[8 * 32 + 64];
    const int b = blockIdx.x;
    const int t = threadIdx.x;

    for (int l = t; l < 900; l += 256) xs[l] = 0.f;
    {
        int d = t >> 5, c = t & 31;
        int e = d + (d >= 4 ? 1 : 0);
        int dy = e / 3 - 1, dx = e % 3 - 1;
        int widx = 2 * (dx + 1) + 10 * (dy + 1);
        w1s[t] = W1[widx * 32 + c];
        if (t < 32) { w1s[256 + t] = root1[t]; w1s[288 + t] = b1[t]; }
    }
    __syncthreads();
    const float* xb = x + (size_t)b * 784;
    for (int l = t; l < 784; l += 256) {
        int y = l / 28, xx = l % 28;
        xs[(y + 1) * 30 + xx + 1] = xb[l];
    }
    __syncthreads();

    if (t >= 196) return;
    int py = t / 14, px = t % 14;
    int xbse[4];
    float xc[4], inv[4];
    #pragma unroll
    for (int p = 0; p < 4; ++p) {
        int sy = p >> 1, sx = p & 1;
        int y = 2 * py + sy, xx = 2 * px + sx;
        xbse[p] = (y + 1) * 30 + xx + 1;
        xc[p] = xs[xbse[p]];
        int nvy = 3 - (y == 0) - (y == 27);
        int nvx = 3 - (xx == 0) - (xx == 27);
        inv[p] = 1.f / (float)(nvy * nvx - 1);
    }
    const float4* w4 = (const float4*)w1s;
    float* outp = p1 + ((size_t)b * 196 + t) * 32;

    #pragma unroll
    for (int h = 0; h < 2; ++h) {
        float4 acc[4][4];
        #pragma unroll
        for (int p = 0; p < 4; ++p)
            #pragma unroll
            for (int q = 0; q < 4; ++q) acc[p][q] = make_float4(0.f, 0.f, 0.f, 0.f);
        #pragma unroll
        for (int d = 0; d < 8; ++d) {
            int e = d + (d >= 4 ? 1 : 0);
            int od = (e / 3 - 1) * 30 + (e % 3 - 1);
            float4 w0 = w4[d * 8 + h * 4 + 0];
            float4 w1 = w4[d * 8 + h * 4 + 1];
            float4 w2 = w4[d * 8 + h * 4 + 2];
            float4 w3 = w4[d * 8 + h * 4 + 3];
            #pragma unroll
            for (int p = 0; p < 4; ++p) {
                float xv = xs[xbse[p] + od];
                acc[p][0].x += xv * w0.x; acc[p][0].y += xv * w0.y; acc[p][0].z += xv * w0.z; acc[p][0].w += xv * w0.w;
                acc[p][1].x += xv * w1.x; acc[p][1].y += xv * w1.y; acc[p][1].z += xv * w1.z; acc[p][1].w += xv * w1.w;
                acc[p][2].x += xv * w2.x; acc[p][2].y += xv * w2.y; acc[p][2].z += xv * w2.z; acc[p][2].w += xv * w2.w;
                acc[p][3].x += xv * w3.x; acc[p][3].y += xv * w3.y; acc[p][3].z += xv * w3.z; acc[p][3].w += xv * w3.w;
            }
        }
        #pragma unroll
        for (int q = 0; q < 4; ++q) {
            float4 rt = w4[64 + h * 4 + q];
            float4 bs = w4[72 + h * 4 + q];
            float4 m = make_float4(-1e30f, -1e30f, -1e30f, -1e30f);
            #pragma unroll
            for (int p = 0; p < 4; ++p) {
                float4 v;
                v.x = elu1(acc[p][q].x * inv[p] + xc[p] * rt.x + bs.x);
                v.y = elu1(acc[p][q].y * inv[p] + xc[p] * rt.y + bs.y);
                v.z = elu1(acc[p][q].z * inv[p] + xc[p] * rt.z + bs.z);
                v.w = elu1(acc[p][q].w * inv[p] + xc[p] * rt.w + bs.w);
                m.x = fmaxf(m.x, v.x); m.y = fmaxf(m.y, v.y);
                m.z = fmaxf(m.z, v.z); m.w = fmaxf(m.w, v.w);
            }
            *(float4*)(outp + h * 16 + q * 4) = m;
        }
    }
}

// ============ Kernel 2: conv2 (9-dir, 32->64) + ELU + 2x2 pool ============
// v8: thread = 8 positions (2x4) x 8 out-ch. 28 tiles x 8 cg = 224 active.
// W per dir staged whole into [32][72] dbuf (B/FMA 1.0 vs r7 1.5).
// Exact d-outer / i-ascending order preserved (bit-exact vs np).
__global__ __launch_bounds__(256) void k2_conv2_pool(
    const float* __restrict__ p1, const float* __restrict__ W2,
    const float* __restrict__ root2, const float* __restrict__ b2,
    float* __restrict__ p2) {
    __shared__ float xs[9216];          // 256 nodes * 36, i4-swizzled (r6 layout)
    __shared__ float wb[2][2304];       // [32 rows][72pad] per direction
    const int b = blockIdx.x;
    const int t = threadIdx.x;
    int tile = t >> 3; if (tile > 27) tile = 27;
    const int cg = t & 7;

    static const int widx_t[8] = {0, 2, 4, 10, 14, 20, 22, 24};
    static const int ddy[8] = {-1,-1,-1, 0, 0, 1, 1, 1};
    static const int ddx[8] = {-1, 0, 1,-1, 1,-1, 0, 1};

    // stage dir-0 weights into wb[0]: [i][72], cols 0..63
    {
        const float4* s4 = (const float4*)W2;
        float4 v0 = s4[t], v1 = s4[t + 256];
        *(float4*)(wb[0] + (t >> 4) * 72 + (t & 15) * 4) = v0;
        *(float4*)(wb[0] + ((t + 256) >> 4) * 72 + (t & 15) * 4) = v1;
    }
    for (int l = t; l < 9216; l += 256) xs[l] = 0.f;
    __syncthreads();
    // interior fill: swizzled i-block scatter (r6 verbatim)
    {
        const float* src = p1 + (size_t)b * 6272;
        for (int l = t; l < 6272; l += 256) {
            int node = l >> 5, i = l & 31;
            int y = node / 14, xx = node - y * 14;
            int np = (y + 1) * 16 + xx + 1;
            xs[np * 36 + 4 * ((i >> 2) ^ ((np >> 4) & 7)) + (i & 3)] = src[l];
        }
    }
    __syncthreads();

    const int py = tile >> 2, q = tile & 3;
    int npb[8]; float invd[8];
    #pragma unroll
    for (int p = 0; p < 8; ++p) {
        int r = p >> 2, c = p & 3;
        int gy = 2 * py + r, gx = 4 * q + c;        // gx up to 15 for q=3 (garbage, masked at store)
        npb[p] = (gy + 1) * 16 + gx + 1;
        int gxc = gx > 13 ? 13 : gx;
        int nvy = 3 - (gy == 0) - (gy == 13);
        int nvx = 3 - (gxc == 0) - (gxc == 13);
        invd[p] = 1.f / (float)(nvy * nvx - 1);
    }

    float4 acc[8][2];
    #pragma unroll
    for (int p = 0; p < 8; ++p) { acc[p][0] = make_float4(0,0,0,0); acc[p][1] = make_float4(0,0,0,0); }

    for (int d = 0; d < 9; ++d) {
        float4 pf0, pf1;
        if (d < 8) {
            const float* nsrc = (d + 1 == 8) ? root2 : (W2 + (size_t)widx_t[d + 1] * 2048);
            pf0 = ((const float4*)nsrc)[t];
            pf1 = ((const float4*)nsrc)[t + 256];
        }
        if (d == 8) {
            #pragma unroll
            for (int p = 0; p < 8; ++p) {
                acc[p][0].x *= invd[p]; acc[p][0].y *= invd[p]; acc[p][0].z *= invd[p]; acc[p][0].w *= invd[p];
                acc[p][1].x *= invd[p]; acc[p][1].y *= invd[p]; acc[p][1].z *= invd[p]; acc[p][1].w *= invd[p];
            }
        }
        int dnode = (d < 8) ? (ddy[d] * 16 + ddx[d]) : 0;
        int ax[8], sz[8];
        #pragma unroll
        for (int p = 0; p < 8; ++p) {
            int np = npb[p] + dnode;
            ax[p] = np * 36;
            sz[p] = (np >> 4) & 7;
        }
        const float* wcur = wb[d & 1];
        #pragma unroll 2
        for (int i4 = 0; i4 < 8; ++i4) {
            float xa[8][4];
            #pragma unroll
            for (int p = 0; p < 8; ++p) {
                float4 v = *(const float4*)(xs + ax[p] + 4 * (i4 ^ sz[p]));
                xa[p][0] = v.x; xa[p][1] = v.y; xa[p][2] = v.z; xa[p][3] = v.w;
            }
            #pragma unroll
            for (int ii = 0; ii < 4; ++ii) {
                const float* wr = wcur + (i4 * 4 + ii) * 72 + cg * 8;
                float4 w0 = *(const float4*)wr;
                float4 w1 = *(const float4*)(wr + 4);
                #pragma unroll
                for (int p = 0; p < 8; ++p) {
                    float xv = xa[p][ii];
                    acc[p][0].x += xv * w0.x; acc[p][0].y += xv * w0.y;
                    acc[p][0].z += xv * w0.z; acc[p][0].w += xv * w0.w;
                    acc[p][1].x += xv * w1.x; acc[p][1].y += xv * w1.y;
                    acc[p][1].z += xv * w1.z; acc[p][1].w += xv * w1.w;
                }
            }
        }
        if (d < 8) {
            float* wn = wb[(d + 1) & 1];
            *(float4*)(wn + (t >> 4) * 72 + (t & 15) * 4) = pf0;
            *(float4*)(wn + ((t + 256) >> 4) * 72 + (t & 15) * 4) = pf1;
        }
        __syncthreads();
    }

    // epilogue: +bias, ELU, 2x2 pool in regs; thread stores cells (py, 2q) and (py, 2q+1)
    if (t < 224) {
        float4 bs0 = *(const float4*)(b2 + cg * 8);
        float4 bs1 = *(const float4*)(b2 + cg * 8 + 4);
        float* outb = p2 + (size_t)b * 3136;
        #pragma unroll
        for (int cc = 0; cc < 2; ++cc) {
            int cellcol = 2 * q + cc;
            if (cellcol > 6) continue;
            float4 m0 = make_float4(-1e30f,-1e30f,-1e30f,-1e30f);
            float4 m1 = m0;
            #pragma unroll
            for (int r = 0; r < 2; ++r)
            #pragma unroll
            for (int c2 = 0; c2 < 2; ++c2) {
                int p = r * 4 + cc * 2 + c2;
                float4 v0, v1;
                v0.x = elu1(acc[p][0].x + bs0.x); v0.y = elu1(acc[p][0].y + bs0.y);
                v0.z = elu1(acc[p][0].z + bs0.z); v0.w = elu1(acc[p][0].w + bs0.w);
                v1.x = elu1(acc[p][1].x + bs1.x); v1.y = elu1(acc[p][1].y + bs1.y);
                v1.z = elu1(acc[p][1].z + bs1.z); v1.w = elu1(acc[p][1].w + bs1.w);
                m0.x = fmaxf(m0.x, v0.x); m0.y = fmaxf(m0.y, v0.y);
                m0.z = fmaxf(m0.z, v0.z); m0.w = fmaxf(m0.w, v0.w);
                m1.x = fmaxf(m1.x, v1.x); m1.y = fmaxf(m1.y, v1.y);
                m1.z = fmaxf(m1.z, v1.z); m1.w = fmaxf(m1.w, v1.w);
            }
            int cell = py * 7 + cellcol;
            *(float4*)(outb + cell * 64 + cg * 8)     = m0;
            *(float4*)(outb + cell * 64 + cg * 8 + 4) = m1;
        }
    }
}

// ============ Kernel 3a: fc1 split-K GEMM, 64x64 tile, 4x4/thread, B from global ============
// Only A in LDS (transposed). B rows read from global per k (L2-resident, 16-lane
// multicast; addresses loop-independent -> compiler hoists loads). grid (8,8,12)=768 blocks.
__global__ __launch_bounds__(256) void k3a_fc1(
    const float* __restrict__ A, const float* __restrict__ B,
    float* __restrict__ part) {
    __shared__ float As[2][16][68];
    const int t = threadIdx.x;
    const int tx = t & 15, ty = t >> 4;
    const int n0 = blockIdx.x * 64, m0 = blockIdx.y * 64, kz = blockIdx.z;
    const int k0 = kz * 272;
    const int steps = ((kz == 11) ? 144 : 272) >> 4;
    const int sm = t & 63, k4 = t >> 6;

    const float* Ap = A + (size_t)(m0 + sm) * 3136 + k0 + k4 * 4;
    const float* Bp = B + (size_t)k0 * 512 + n0 + tx * 4;

    {
        float4 av = *(const float4*)Ap;
        As[0][k4 * 4 + 0][sm] = av.x; As[0][k4 * 4 + 1][sm] = av.y;
        As[0][k4 * 4 + 2][sm] = av.z; As[0][k4 * 4 + 3][sm] = av.w;
    }
    __syncthreads();

    float acc[4][4];
    #pragma unroll
    for (int r = 0; r < 4; ++r)
        #pragma unroll
        for (int c = 0; c < 4; ++c) acc[r][c] = 0.f;

    int cur = 0;
    for (int s = 0; s < steps; ++s) {
        float4 anext;
        if (s + 1 < steps) anext = *(const float4*)(Ap + (s + 1) * 16);
        #pragma unroll
        for (int k = 0; k < 16; ++k) {
            float4 a4 = *(const float4*)&As[cur][k][ty * 4];
            float4 b4 = *(const float4*)(Bp + (size_t)(s * 16 + k) * 512);
            acc[0][0] += a4.x * b4.x; acc[0][1] += a4.x * b4.y; acc[0][2] += a4.x * b4.z; acc[0][3] += a4.x * b4.w;
            acc[1][0] += a4.y * b4.x; acc[1][1] += a4.y * b4.y; acc[1][2] += a4.y * b4.z; acc[1][3] += a4.y * b4.w;
            acc[2][0] += a4.z * b4.x; acc[2][1] += a4.z * b4.y; acc[2][2] += a4.z * b4.z; acc[2][3] += a4.z * b4.w;
            acc[3][0] += a4.w * b4.x; acc[3][1] += a4.w * b4.y; acc[3][2] += a4.w * b4.z; acc[3][3] += a4.w * b4.w;
        }
        if (s + 1 < steps) {
            const int nxt = cur ^ 1;
            As[nxt][k4 * 4 + 0][sm] = anext.x; As[nxt][k4 * 4 + 1][sm] = anext.y;
            As[nxt][k4 * 4 + 2][sm] = anext.z; As[nxt][k4 * 4 + 3][sm] = anext.w;
            cur = nxt;
        }
        __syncthreads();
    }

    float* pbase = part + ((size_t)kz * 512 + m0 + ty * 4) * 512 + n0;
    #pragma unroll
    for (int r = 0; r < 4; ++r)
        *(float4*)(pbase + (size_t)r * 512 + tx * 4) =
            make_float4(acc[r][0], acc[r][1], acc[r][2], acc[r][3]);
}

// ============ Kernel 34: reduce fc1 partials + bias + ELU, then fc2 + ELU + lsm ============
__global__ __launch_bounds__(256) void k34_reduce_fc2_lsm(
    const float* __restrict__ part, const float* __restrict__ fc1b,
    const float* __restrict__ w, const float* __restrict__ fc2b,
    float* __restrict__ out, int KZ) {
    __shared__ float red[4][10];
    const int b = blockIdx.x, t = threadIdx.x;

    float a0 = fc1b[t], a1 = fc1b[t + 256];
    for (int kz = 0; kz < KZ; ++kz) {
        const float* pr = part + ((size_t)kz * 512 + b) * 512;
        a0 += pr[t]; a1 += pr[t + 256];
    }
    a0 = elu1(a0); a1 = elu1(a1);

    float acc[10];
    #pragma unroll
    for (int o = 0; o < 10; ++o)
        acc[o] = a0 * w[t * 10 + o] + a1 * w[(t + 256) * 10 + o];
    #pragma unroll
    for (int s = 32; s; s >>= 1)
        #pragma unroll
        for (int o = 0; o < 10; ++o) acc[o] += __shfl_xor(acc[o], s, 64);
    if ((t & 63) == 0) {
        #pragma unroll
        for (int o = 0; o < 10; ++o) red[t >> 6][o] = acc[o];
    }
    __syncthreads();
    if (t == 0) {
        float v[10], m = -1e30f;
        #pragma unroll
        for (int o = 0; o < 10; ++o) {
            float s = red[0][o] + red[1][o] + red[2][o] + red[3][o] + fc2b[o];
            v[o] = elu1(s);
            m = fmaxf(m, v[o]);
        }
        float ssum = 0.f;
        #pragma unroll
        for (int o = 0; o < 10; ++o) ssum += expf(v[o] - m);
        float lse = m + logf(ssum);
        #pragma unroll
        for (int o = 0; o < 10; ++o) out[(size_t)b * 10 + o] = v[o] - lse;
    }
}

extern "C" void kernel_launch(void* const* d_in, const int* in_sizes, int n_in,
                              void* d_out, int out_size, void* d_ws, size_t ws_size,
                              hipStream_t stream) {
    const float* x     = (const float*)d_in[0];
    const float* W1    = (const float*)d_in[3];
    const float* root1 = (const float*)d_in[4];
    const float* b1v   = (const float*)d_in[5];
    const float* W2    = (const float*)d_in[6];
    const float* root2 = (const float*)d_in[7];
    const float* b2v   = (const float*)d_in[8];
    const float* fc1w  = (const float*)d_in[9];
    const float* fc1b  = (const float*)d_in[10];
    const float* fc2w  = (const float*)d_in[11];
    const float* fc2b  = (const float*)d_in[12];

    float* ws = (float*)d_ws;
    float* p1 = ws;                                   // 3,211,264 f
    float* p2 = p1 + (size_t)BATCH * 196 * 32;        // 1,605,632 f
    float* part = p1;                                 // p1 dead after k2; 12*262144 fits

    k1_conv1_pool<<<dim3(BATCH), 256, 0, stream>>>(x, W1, root1, b1v, p1);
    k2_conv2_pool<<<dim3(BATCH), 256, 0, stream>>>(p1, W2, root2, b2v, p2);
    k3a_fc1<<<dim3(8, 8, 12), 256, 0, stream>>>(p2, fc1w, part);
    k34_reduce_fc2_lsm<<<dim3(BATCH), 256, 0, stream>>>(part, fc1b, fc2w, fc2b, (float*)d_out, 12);
}

// Round 10
// 127.614 us; speedup vs baseline: 1.0542x; 1.0542x over previous
//
#include <hip/hip_runtime.h>
#include <math.h>

#define BATCH 512

__device__ __forceinline__ float elu1(float v) {
    return v > 0.f ? v : expm1f(v);
}

// ============ Kernel 1: conv1 (9-dir stencil, 1->32) + ELU + 2x2 pool ============
__global__ __launch_bounds__(256) void k1_conv1_pool(
    const float* __restrict__ x, const float* __restrict__ W1,
    const float* __restrict__ root1, const float* __restrict__ b1,
    float* __restrict__ p1) {
    __shared__ float xs[900];            // [30][30] zero-padded image
    __shared__ float w1s[8 * 32 + 64];
    const int b = blockIdx.x;
    const int t = threadIdx.x;

    for (int l = t; l < 900; l += 256) xs[l] = 0.f;
    {
        int d = t >> 5, c = t & 31;
        int e = d + (d >= 4 ? 1 : 0);
        int dy = e / 3 - 1, dx = e % 3 - 1;
        int widx = 2 * (dx + 1) + 10 * (dy + 1);
        w1s[t] = W1[widx * 32 + c];
        if (t < 32) { w1s[256 + t] = root1[t]; w1s[288 + t] = b1[t]; }
    }
    __syncthreads();
    const float* xb = x + (size_t)b * 784;
    for (int l = t; l < 784; l += 256) {
        int y = l / 28, xx = l % 28;
        xs[(y + 1) * 30 + xx + 1] = xb[l];
    }
    __syncthreads();

    if (t >= 196) return;
    int py = t / 14, px = t % 14;
    int xbse[4];
    float xc[4], inv[4];
    #pragma unroll
    for (int p = 0; p < 4; ++p) {
        int sy = p >> 1, sx = p & 1;
        int y = 2 * py + sy, xx = 2 * px + sx;
        xbse[p] = (y + 1) * 30 + xx + 1;
        xc[p] = xs[xbse[p]];
        int nvy = 3 - (y == 0) - (y == 27);
        int nvx = 3 - (xx == 0) - (xx == 27);
        inv[p] = 1.f / (float)(nvy * nvx - 1);
    }
    const float4* w4 = (const float4*)w1s;
    float* outp = p1 + ((size_t)b * 196 + t) * 32;

    #pragma unroll
    for (int h = 0; h < 2; ++h) {
        float4 acc[4][4];
        #pragma unroll
        for (int p = 0; p < 4; ++p)
            #pragma unroll
            for (int q = 0; q < 4; ++q) acc[p][q] = make_float4(0.f, 0.f, 0.f, 0.f);
        #pragma unroll
        for (int d = 0; d < 8; ++d) {
            int e = d + (d >= 4 ? 1 : 0);
            int od = (e / 3 - 1) * 30 + (e % 3 - 1);
            float4 w0 = w4[d * 8 + h * 4 + 0];
            float4 w1 = w4[d * 8 + h * 4 + 1];
            float4 w2 = w4[d * 8 + h * 4 + 2];
            float4 w3 = w4[d * 8 + h * 4 + 3];
            #pragma unroll
            for (int p = 0; p < 4; ++p) {
                float xv = xs[xbse[p] + od];
                acc[p][0].x += xv * w0.x; acc[p][0].y += xv * w0.y; acc[p][0].z += xv * w0.z; acc[p][0].w += xv * w0.w;
                acc[p][1].x += xv * w1.x; acc[p][1].y += xv * w1.y; acc[p][1].z += xv * w1.z; acc[p][1].w += xv * w1.w;
                acc[p][2].x += xv * w2.x; acc[p][2].y += xv * w2.y; acc[p][2].z += xv * w2.z; acc[p][2].w += xv * w2.w;
                acc[p][3].x += xv * w3.x; acc[p][3].y += xv * w3.y; acc[p][3].z += xv * w3.z; acc[p][3].w += xv * w3.w;
            }
        }
        #pragma unroll
        for (int q = 0; q < 4; ++q) {
            float4 rt = w4[64 + h * 4 + q];
            float4 bs = w4[72 + h * 4 + q];
            float4 m = make_float4(-1e30f, -1e30f, -1e30f, -1e30f);
            #pragma unroll
            for (int p = 0; p < 4; ++p) {
                float4 v;
                v.x = elu1(acc[p][q].x * inv[p] + xc[p] * rt.x + bs.x);
                v.y = elu1(acc[p][q].y * inv[p] + xc[p] * rt.y + bs.y);
                v.z = elu1(acc[p][q].z * inv[p] + xc[p] * rt.z + bs.z);
                v.w = elu1(acc[p][q].w * inv[p] + xc[p] * rt.w + bs.w);
                m.x = fmaxf(m.x, v.x); m.y = fmaxf(m.y, v.y);
                m.z = fmaxf(m.z, v.z); m.w = fmaxf(m.w, v.w);
            }
            *(float4*)(outp + h * 16 + q * 4) = m;
        }
    }
}

// ============ Kernel 2: conv2 (9-dir, 32->64) + ELU + 2x2 pool ============
// v9 = v8 compute structure + SINGLE-buffered W (prefetch dir d+1 to regs during
// compute of d; barrier/write/barrier). LDS 45KB -> 3 blocks/CU (was 2).
// Exact d-outer / i-ascending order preserved (bit-exact vs np).
__global__ __launch_bounds__(256) void k2_conv2_pool(
    const float* __restrict__ p1, const float* __restrict__ W2,
    const float* __restrict__ root2, const float* __restrict__ b2,
    float* __restrict__ p2) {
    __shared__ float xs[9216];          // 256 nodes * 36, i4-swizzled (r6 layout)
    __shared__ float wb[2304];          // [32 rows][72pad], single buffer
    const int b = blockIdx.x;
    const int t = threadIdx.x;
    int tile = t >> 3; if (tile > 27) tile = 27;
    const int cg = t & 7;

    static const int widx_t[8] = {0, 2, 4, 10, 14, 20, 22, 24};
    static const int ddy[8] = {-1,-1,-1, 0, 0, 1, 1, 1};
    static const int ddx[8] = {-1, 0, 1,-1, 1,-1, 0, 1};

    // stage dir-0 weights into wb: [i][72], cols 0..63
    {
        const float4* s4 = (const float4*)W2;
        float4 v0 = s4[t], v1 = s4[t + 256];
        *(float4*)(wb + (t >> 4) * 72 + (t & 15) * 4) = v0;
        *(float4*)(wb + ((t + 256) >> 4) * 72 + (t & 15) * 4) = v1;
    }
    for (int l = t; l < 9216; l += 256) xs[l] = 0.f;
    __syncthreads();
    // interior fill: swizzled i-block scatter (r6 verbatim)
    {
        const float* src = p1 + (size_t)b * 6272;
        for (int l = t; l < 6272; l += 256) {
            int node = l >> 5, i = l & 31;
            int y = node / 14, xx = node - y * 14;
            int np = (y + 1) * 16 + xx + 1;
            xs[np * 36 + 4 * ((i >> 2) ^ ((np >> 4) & 7)) + (i & 3)] = src[l];
        }
    }
    __syncthreads();

    const int py = tile >> 2, q = tile & 3;
    int npb[8]; float invd[8];
    #pragma unroll
    for (int p = 0; p < 8; ++p) {
        int r = p >> 2, c = p & 3;
        int gy = 2 * py + r, gx = 4 * q + c;
        npb[p] = (gy + 1) * 16 + gx + 1;
        int gxc = gx > 13 ? 13 : gx;
        int nvy = 3 - (gy == 0) - (gy == 13);
        int nvx = 3 - (gxc == 0) - (gxc == 13);
        invd[p] = 1.f / (float)(nvy * nvx - 1);
    }

    float4 acc[8][2];
    #pragma unroll
    for (int p = 0; p < 8; ++p) { acc[p][0] = make_float4(0,0,0,0); acc[p][1] = make_float4(0,0,0,0); }

    for (int d = 0; d < 9; ++d) {
        float4 pf0, pf1;
        if (d < 8) {
            const float* nsrc = (d + 1 == 8) ? root2 : (W2 + (size_t)widx_t[d + 1] * 2048);
            pf0 = ((const float4*)nsrc)[t];
            pf1 = ((const float4*)nsrc)[t + 256];
        }
        if (d == 8) {
            #pragma unroll
            for (int p = 0; p < 8; ++p) {
                acc[p][0].x *= invd[p]; acc[p][0].y *= invd[p]; acc[p][0].z *= invd[p]; acc[p][0].w *= invd[p];
                acc[p][1].x *= invd[p]; acc[p][1].y *= invd[p]; acc[p][1].z *= invd[p]; acc[p][1].w *= invd[p];
            }
        }
        int dnode = (d < 8) ? (ddy[d] * 16 + ddx[d]) : 0;
        int ax[8], sz[8];
        #pragma unroll
        for (int p = 0; p < 8; ++p) {
            int np = npb[p] + dnode;
            ax[p] = np * 36;
            sz[p] = (np >> 4) & 7;
        }
        #pragma unroll 2
        for (int i4 = 0; i4 < 8; ++i4) {
            float xa[8][4];
            #pragma unroll
            for (int p = 0; p < 8; ++p) {
                float4 v = *(const float4*)(xs + ax[p] + 4 * (i4 ^ sz[p]));
                xa[p][0] = v.x; xa[p][1] = v.y; xa[p][2] = v.z; xa[p][3] = v.w;
            }
            #pragma unroll
            for (int ii = 0; ii < 4; ++ii) {
                const float* wr = wb + (i4 * 4 + ii) * 72 + cg * 8;
                float4 w0 = *(const float4*)wr;
                float4 w1 = *(const float4*)(wr + 4);
                #pragma unroll
                for (int p = 0; p < 8; ++p) {
                    float xv = xa[p][ii];
                    acc[p][0].x += xv * w0.x; acc[p][0].y += xv * w0.y;
                    acc[p][0].z += xv * w0.z; acc[p][0].w += xv * w0.w;
                    acc[p][1].x += xv * w1.x; acc[p][1].y += xv * w1.y;
                    acc[p][1].z += xv * w1.z; acc[p][1].w += xv * w1.w;
                }
            }
        }
        if (d < 8) {
            __syncthreads();   // everyone done reading dir d
            *(float4*)(wb + (t >> 4) * 72 + (t & 15) * 4) = pf0;
            *(float4*)(wb + ((t + 256) >> 4) * 72 + (t & 15) * 4) = pf1;
            __syncthreads();   // dir d+1 fully written
        }
    }

    // epilogue: +bias, ELU, 2x2 pool in regs; thread stores cells (py, 2q) and (py, 2q+1)
    if (t < 224) {
        float4 bs0 = *(const float4*)(b2 + cg * 8);
        float4 bs1 = *(const float4*)(b2 + cg * 8 + 4);
        float* outb = p2 + (size_t)b * 3136;
        #pragma unroll
        for (int cc = 0; cc < 2; ++cc) {
            int cellcol = 2 * q + cc;
            if (cellcol > 6) continue;
            float4 m0 = make_float4(-1e30f,-1e30f,-1e30f,-1e30f);
            float4 m1 = m0;
            #pragma unroll
            for (int r = 0; r < 2; ++r)
            #pragma unroll
            for (int c2 = 0; c2 < 2; ++c2) {
                int p = r * 4 + cc * 2 + c2;
                float4 v0, v1;
                v0.x = elu1(acc[p][0].x + bs0.x); v0.y = elu1(acc[p][0].y + bs0.y);
                v0.z = elu1(acc[p][0].z + bs0.z); v0.w = elu1(acc[p][0].w + bs0.w);
                v1.x = elu1(acc[p][1].x + bs1.x); v1.y = elu1(acc[p][1].y + bs1.y);
                v1.z = elu1(acc[p][1].z + bs1.z); v1.w = elu1(acc[p][1].w + bs1.w);
                m0.x = fmaxf(m0.x, v0.x); m0.y = fmaxf(m0.y, v0.y);
                m0.z = fmaxf(m0.z, v0.z); m0.w = fmaxf(m0.w, v0.w);
                m1.x = fmaxf(m1.x, v1.x); m1.y = fmaxf(m1.y, v1.y);
                m1.z = fmaxf(m1.z, v1.z); m1.w = fmaxf(m1.w, v1.w);
            }
            int cell = py * 7 + cellcol;
            *(float4*)(outb + cell * 64 + cg * 8)     = m0;
            *(float4*)(outb + cell * 64 + cg * 8 + 4) = m1;
        }
    }
}

// ============ Kernel 3a: fc1 split-K GEMM, 64x64 tile, 4x4/thread, BK=16, KZ=12 ============
// (r7 known-good version: both A and B staged in LDS, double-buffered.)
__global__ __launch_bounds__(256) void k3a_fc1(
    const float* __restrict__ A, const float* __restrict__ B,
    float* __restrict__ part) {
    __shared__ float As[2][16][64];
    __shared__ float Bs[2][16][72];
    const int t = threadIdx.x;
    const int tx = t & 15, ty = t >> 4;
    const int n0 = blockIdx.x * 64, m0 = blockIdx.y * 64;
    const int k0 = blockIdx.z * 272;
    const int steps = ((blockIdx.z == 11) ? 144 : 272) >> 4;

    const int sm = t & 63, k4 = t >> 6;       // A staging: row, 4-float chunk
    const int sk = t >> 4, sc = t & 15;       // B staging: k-row, col-f4
    const float* Ap = A + (size_t)(m0 + sm) * 3136 + k0 + k4 * 4;
    const float* Bp = B + (size_t)(k0 + sk) * 512 + n0 + sc * 4;

    {
        float4 av = *(const float4*)Ap;
        float4 bv = *(const float4*)Bp;
        As[0][k4 * 4 + 0][sm] = av.x; As[0][k4 * 4 + 1][sm] = av.y;
        As[0][k4 * 4 + 2][sm] = av.z; As[0][k4 * 4 + 3][sm] = av.w;
        *(float4*)&Bs[0][sk][sc * 4] = bv;
    }
    __syncthreads();

    float acc[4][4];
    #pragma unroll
    for (int r = 0; r < 4; ++r)
        #pragma unroll
        for (int c = 0; c < 4; ++c) acc[r][c] = 0.f;

    for (int s = 0; s < steps; ++s) {
        float4 a0, b0;
        if (s + 1 < steps) {
            a0 = *(const float4*)(Ap + (s + 1) * 16);
            b0 = *(const float4*)(Bp + (size_t)(s + 1) * 16 * 512);
        }
        const int cur = s & 1;
        #pragma unroll
        for (int k = 0; k < 16; ++k) {
            float4 a4 = *(const float4*)&As[cur][k][ty * 4];
            float4 b4 = *(const float4*)&Bs[cur][k][tx * 4];
            acc[0][0] += a4.x * b4.x; acc[0][1] += a4.x * b4.y; acc[0][2] += a4.x * b4.z; acc[0][3] += a4.x * b4.w;
            acc[1][0] += a4.y * b4.x; acc[1][1] += a4.y * b4.y; acc[1][2] += a4.y * b4.z; acc[1][3] += a4.y * b4.w;
            acc[2][0] += a4.z * b4.x; acc[2][1] += a4.z * b4.y; acc[2][2] += a4.z * b4.z; acc[2][3] += a4.z * b4.w;
            acc[3][0] += a4.w * b4.x; acc[3][1] += a4.w * b4.y; acc[3][2] += a4.w * b4.z; acc[3][3] += a4.w * b4.w;
        }
        if (s + 1 < steps) {
            const int nxt = cur ^ 1;
            As[nxt][k4 * 4 + 0][sm] = a0.x; As[nxt][k4 * 4 + 1][sm] = a0.y;
            As[nxt][k4 * 4 + 2][sm] = a0.z; As[nxt][k4 * 4 + 3][sm] = a0.w;
            *(float4*)&Bs[nxt][sk][sc * 4] = b0;
        }
        __syncthreads();
    }

    float* pbase = part + ((size_t)blockIdx.z * 512 + m0 + ty * 4) * 512 + n0;
    #pragma unroll
    for (int r = 0; r < 4; ++r)
        *(float4*)(pbase + (size_t)r * 512 + tx * 4) =
            make_float4(acc[r][0], acc[r][1], acc[r][2], acc[r][3]);
}

// ============ Kernel 34: reduce fc1 partials + bias + ELU, then fc2 + ELU + lsm ============
__global__ __launch_bounds__(256) void k34_reduce_fc2_lsm(
    const float* __restrict__ part, const float* __restrict__ fc1b,
    const float* __restrict__ w, const float* __restrict__ fc2b,
    float* __restrict__ out, int KZ) {
    __shared__ float red[4][10];
    const int b = blockIdx.x, t = threadIdx.x;

    float a0 = fc1b[t], a1 = fc1b[t + 256];
    for (int kz = 0; kz < KZ; ++kz) {
        const float* pr = part + ((size_t)kz * 512 + b) * 512;
        a0 += pr[t]; a1 += pr[t + 256];
    }
    a0 = elu1(a0); a1 = elu1(a1);

    float acc[10];
    #pragma unroll
    for (int o = 0; o < 10; ++o)
        acc[o] = a0 * w[t * 10 + o] + a1 * w[(t + 256) * 10 + o];
    #pragma unroll
    for (int s = 32; s; s >>= 1)
        #pragma unroll
        for (int o = 0; o < 10; ++o) acc[o] += __shfl_xor(acc[o], s, 64);
    if ((t & 63) == 0) {
        #pragma unroll
        for (int o = 0; o < 10; ++o) red[t >> 6][o] = acc[o];
    }
    __syncthreads();
    if (t == 0) {
        float v[10], m = -1e30f;
        #pragma unroll
        for (int o = 0; o < 10; ++o) {
            float s = red[0][o] + red[1][o] + red[2][o] + red[3][o] + fc2b[o];
            v[o] = elu1(s);
            m = fmaxf(m, v[o]);
        }
        float ssum = 0.f;
        #pragma unroll
        for (int o = 0; o < 10; ++o) ssum += expf(v[o] - m);
        float lse = m + logf(ssum);
        #pragma unroll
        for (int o = 0; o < 10; ++o) out[(size_t)b * 10 + o] = v[o] - lse;
    }
}

extern "C" void kernel_launch(void* const* d_in, const int* in_sizes, int n_in,
                              void* d_out, int out_size, void* d_ws, size_t ws_size,
                              hipStream_t stream) {
    const float* x     = (const float*)d_in[0];
    const float* W1    = (const float*)d_in[3];
    const float* root1 = (const float*)d_in[4];
    const float* b1v   = (const float*)d_in[5];
    const float* W2    = (const float*)d_in[6];
    const float* root2 = (const float*)d_in[7];
    const float* b2v   = (const float*)d_in[8];
    const float* fc1w  = (const float*)d_in[9];
    const float* fc1b  = (const float*)d_in[10];
    const float* fc2w  = (const float*)d_in[11];
    const float* fc2b  = (const float*)d_in[12];

    float* ws = (float*)d_ws;
    float* p1 = ws;                                   // 3,211,264 f
    float* p2 = p1 + (size_t)BATCH * 196 * 32;        // 1,605,632 f
    float* part = p1;                                 // p1 dead after k2; 12*262144 fits

    k1_conv1_pool<<<dim3(BATCH), 256, 0, stream>>>(x, W1, root1, b1v, p1);
    k2_conv2_pool<<<dim3(BATCH), 256, 0, stream>>>(p1, W2, root2, b2v, p2);
    k3a_fc1<<<dim3(8, 8, 12), 256, 0, stream>>>(p2, fc1w, part);
    k34_reduce_fc2_lsm<<<dim3(BATCH), 256, 0, stream>>>(part, fc1b, fc2w, fc2b, (float*)d_out, 12);
}

// Round 11
// 118.412 us; speedup vs baseline: 1.1361x; 1.0777x over previous
//
#include <hip/hip_runtime.h>
#include <math.h>

#define BATCH 512

__device__ __forceinline__ float elu1(float v) {
    return v > 0.f ? v : expm1f(v);
}

// ============ Kernel 12: FUSED conv1+pool -> conv2+pool (per image) ============
// conv1 output written directly into conv2's swizzled xs LDS (no p1 round trip).
// All arithmetic orders identical to r10 k1/k2 (bit-exact vs np reference).
__global__ __launch_bounds__(256) void k12_conv12(
    const float* __restrict__ x, const float* __restrict__ W1,
    const float* __restrict__ root1, const float* __restrict__ b1,
    const float* __restrict__ W2, const float* __restrict__ root2,
    const float* __restrict__ b2, float* __restrict__ p2) {
    __shared__ float xs1[900];          // [30][30] zero-padded input image
    __shared__ float w1s[320];          // 8 dir vecs [8][32] + root[32] + b[32]
    __shared__ float xs2[9216];         // 256 nodes * 36, i4-swizzled conv2 input
    __shared__ float wb[2304];          // [32][72pad] single-buffered conv2 W
    const int b = blockIdx.x;
    const int t = threadIdx.x;

    static const int widx_t[8] = {0, 2, 4, 10, 14, 20, 22, 24};
    static const int ddy[8] = {-1,-1,-1, 0, 0, 1, 1, 1};
    static const int ddx[8] = {-1, 0, 1,-1, 1,-1, 0, 1};

    // ---- phase 0: stage w1s, wb(dir0), zero xs1 + xs2 border ----
    for (int l = t; l < 900; l += 256) xs1[l] = 0.f;
    {
        int d = t >> 5, c = t & 31;
        int e = d + (d >= 4 ? 1 : 0);
        int dy = e / 3 - 1, dx = e % 3 - 1;
        int widx = 2 * (dx + 1) + 10 * (dy + 1);
        w1s[t] = W1[widx * 32 + c];
        if (t < 32) { w1s[256 + t] = root1[t]; w1s[288 + t] = b1[t]; }
    }
    {
        const float4* s4 = (const float4*)W2;
        float4 v0 = s4[t], v1 = s4[t + 256];
        *(float4*)(wb + (t >> 4) * 72 + (t & 15) * 4) = v0;
        *(float4*)(wb + ((t + 256) >> 4) * 72 + (t & 15) * 4) = v1;
    }
    {
        // zero only the border nodes (rows 0,15 / cols 0,15): 60 nodes x 9 float4.
        // Interior nodes are fully overwritten by conv1 phase; pad floats 32..35
        // are never read (swizzled reads stay in [0,32)).
        float4 z = make_float4(0.f, 0.f, 0.f, 0.f);
        float4* x4 = (float4*)xs2;
        for (int l = t; l < 540; l += 256) {
            int nd = l / 9, s = l - nd * 9;
            int y, xx;
            if (nd < 16)      { y = 0;       xx = nd; }
            else if (nd < 32) { y = 15;      xx = nd - 16; }
            else if (nd < 46) { y = nd - 31; xx = 0; }
            else              { y = nd - 45; xx = 15; }
            x4[(y * 16 + xx) * 9 + s] = z;
        }
    }
    __syncthreads();
    {
        const float* xb = x + (size_t)b * 784;
        for (int l = t; l < 784; l += 256) {
            int y = l / 28, xx = l % 28;
            xs1[(y + 1) * 30 + xx + 1] = xb[l];
        }
    }
    __syncthreads();

    // ---- phase 1: conv1 + ELU + 2x2 pool (r10 k1 verbatim), write into xs2 ----
    if (t < 196) {
        int py = t / 14, px = t % 14;
        int xbse[4];
        float xc[4], inv1[4];
        #pragma unroll
        for (int p = 0; p < 4; ++p) {
            int sy = p >> 1, sx = p & 1;
            int y = 2 * py + sy, xx = 2 * px + sx;
            xbse[p] = (y + 1) * 30 + xx + 1;
            xc[p] = xs1[xbse[p]];
            int nvy = 3 - (y == 0) - (y == 27);
            int nvx = 3 - (xx == 0) - (xx == 27);
            inv1[p] = 1.f / (float)(nvy * nvx - 1);
        }
        const float4* w4 = (const float4*)w1s;
        const int npw = (py + 1) * 16 + px + 1;
        const int szw = (py + 1) & 7;
        float* outp = xs2 + npw * 36;

        #pragma unroll
        for (int h = 0; h < 2; ++h) {
            float4 acc[4][4];
            #pragma unroll
            for (int p = 0; p < 4; ++p)
                #pragma unroll
                for (int q = 0; q < 4; ++q) acc[p][q] = make_float4(0.f, 0.f, 0.f, 0.f);
            #pragma unroll
            for (int d = 0; d < 8; ++d) {
                int e = d + (d >= 4 ? 1 : 0);
                int od = (e / 3 - 1) * 30 + (e % 3 - 1);
                float4 w0 = w4[d * 8 + h * 4 + 0];
                float4 w1 = w4[d * 8 + h * 4 + 1];
                float4 w2 = w4[d * 8 + h * 4 + 2];
                float4 w3 = w4[d * 8 + h * 4 + 3];
                #pragma unroll
                for (int p = 0; p < 4; ++p) {
                    float xv = xs1[xbse[p] + od];
                    acc[p][0].x += xv * w0.x; acc[p][0].y += xv * w0.y; acc[p][0].z += xv * w0.z; acc[p][0].w += xv * w0.w;
                    acc[p][1].x += xv * w1.x; acc[p][1].y += xv * w1.y; acc[p][1].z += xv * w1.z; acc[p][1].w += xv * w1.w;
                    acc[p][2].x += xv * w2.x; acc[p][2].y += xv * w2.y; acc[p][2].z += xv * w2.z; acc[p][2].w += xv * w2.w;
                    acc[p][3].x += xv * w3.x; acc[p][3].y += xv * w3.y; acc[p][3].z += xv * w3.z; acc[p][3].w += xv * w3.w;
                }
            }
            #pragma unroll
            for (int q = 0; q < 4; ++q) {
                float4 rt = w4[64 + h * 4 + q];
                float4 bs = w4[72 + h * 4 + q];
                float4 m = make_float4(-1e30f, -1e30f, -1e30f, -1e30f);
                #pragma unroll
                for (int p = 0; p < 4; ++p) {
                    float4 v;
                    v.x = elu1(acc[p][q].x * inv1[p] + xc[p] * rt.x + bs.x);
                    v.y = elu1(acc[p][q].y * inv1[p] + xc[p] * rt.y + bs.y);
                    v.z = elu1(acc[p][q].z * inv1[p] + xc[p] * rt.z + bs.z);
                    v.w = elu1(acc[p][q].w * inv1[p] + xc[p] * rt.w + bs.w);
                    m.x = fmaxf(m.x, v.x); m.y = fmaxf(m.y, v.y);
                    m.z = fmaxf(m.z, v.z); m.w = fmaxf(m.w, v.w);
                }
                int B = h * 4 + q;                       // i-block 0..7
                *(float4*)(outp + 4 * (B ^ szw)) = m;    // swizzled store
            }
        }
    }
    __syncthreads();

    // ---- phase 2: conv2 + ELU + 2x2 pool (r10 k2 verbatim, xs -> xs2) ----
    int tile = t >> 3; if (tile > 27) tile = 27;
    const int cg = t & 7;
    const int py2 = tile >> 2, q2 = tile & 3;
    int npb[8]; float invd[8];
    #pragma unroll
    for (int p = 0; p < 8; ++p) {
        int r = p >> 2, c = p & 3;
        int gy = 2 * py2 + r, gx = 4 * q2 + c;
        npb[p] = (gy + 1) * 16 + gx + 1;
        int gxc = gx > 13 ? 13 : gx;
        int nvy = 3 - (gy == 0) - (gy == 13);
        int nvx = 3 - (gxc == 0) - (gxc == 13);
        invd[p] = 1.f / (float)(nvy * nvx - 1);
    }

    float4 acc[8][2];
    #pragma unroll
    for (int p = 0; p < 8; ++p) { acc[p][0] = make_float4(0,0,0,0); acc[p][1] = make_float4(0,0,0,0); }

    for (int d = 0; d < 9; ++d) {
        float4 pf0, pf1;
        if (d < 8) {
            const float* nsrc = (d + 1 == 8) ? root2 : (W2 + (size_t)widx_t[d + 1] * 2048);
            pf0 = ((const float4*)nsrc)[t];
            pf1 = ((const float4*)nsrc)[t + 256];
        }
        if (d == 8) {
            #pragma unroll
            for (int p = 0; p < 8; ++p) {
                acc[p][0].x *= invd[p]; acc[p][0].y *= invd[p]; acc[p][0].z *= invd[p]; acc[p][0].w *= invd[p];
                acc[p][1].x *= invd[p]; acc[p][1].y *= invd[p]; acc[p][1].z *= invd[p]; acc[p][1].w *= invd[p];
            }
        }
        int dnode = (d < 8) ? (ddy[d] * 16 + ddx[d]) : 0;
        int ax[8], sz[8];
        #pragma unroll
        for (int p = 0; p < 8; ++p) {
            int np = npb[p] + dnode;
            ax[p] = np * 36;
            sz[p] = (np >> 4) & 7;
        }
        #pragma unroll 2
        for (int i4 = 0; i4 < 8; ++i4) {
            float xa[8][4];
            #pragma unroll
            for (int p = 0; p < 8; ++p) {
                float4 v = *(const float4*)(xs2 + ax[p] + 4 * (i4 ^ sz[p]));
                xa[p][0] = v.x; xa[p][1] = v.y; xa[p][2] = v.z; xa[p][3] = v.w;
            }
            #pragma unroll
            for (int ii = 0; ii < 4; ++ii) {
                const float* wr = wb + (i4 * 4 + ii) * 72 + cg * 8;
                float4 w0 = *(const float4*)wr;
                float4 w1 = *(const float4*)(wr + 4);
                #pragma unroll
                for (int p = 0; p < 8; ++p) {
                    float xv = xa[p][ii];
                    acc[p][0].x += xv * w0.x; acc[p][0].y += xv * w0.y;
                    acc[p][0].z += xv * w0.z; acc[p][0].w += xv * w0.w;
                    acc[p][1].x += xv * w1.x; acc[p][1].y += xv * w1.y;
                    acc[p][1].z += xv * w1.z; acc[p][1].w += xv * w1.w;
                }
            }
        }
        if (d < 8) {
            __syncthreads();   // everyone done reading dir d
            *(float4*)(wb + (t >> 4) * 72 + (t & 15) * 4) = pf0;
            *(float4*)(wb + ((t + 256) >> 4) * 72 + (t & 15) * 4) = pf1;
            __syncthreads();   // dir d+1 fully written
        }
    }

    if (t < 224) {
        float4 bs0 = *(const float4*)(b2 + cg * 8);
        float4 bs1 = *(const float4*)(b2 + cg * 8 + 4);
        float* outb = p2 + (size_t)b * 3136;
        #pragma unroll
        for (int cc = 0; cc < 2; ++cc) {
            int cellcol = 2 * q2 + cc;
            if (cellcol > 6) continue;
            float4 m0 = make_float4(-1e30f,-1e30f,-1e30f,-1e30f);
            float4 m1 = m0;
            #pragma unroll
            for (int r = 0; r < 2; ++r)
            #pragma unroll
            for (int c2 = 0; c2 < 2; ++c2) {
                int p = r * 4 + cc * 2 + c2;
                float4 v0, v1;
                v0.x = elu1(acc[p][0].x + bs0.x); v0.y = elu1(acc[p][0].y + bs0.y);
                v0.z = elu1(acc[p][0].z + bs0.z); v0.w = elu1(acc[p][0].w + bs0.w);
                v1.x = elu1(acc[p][1].x + bs1.x); v1.y = elu1(acc[p][1].y + bs1.y);
                v1.z = elu1(acc[p][1].z + bs1.z); v1.w = elu1(acc[p][1].w + bs1.w);
                m0.x = fmaxf(m0.x, v0.x); m0.y = fmaxf(m0.y, v0.y);
                m0.z = fmaxf(m0.z, v0.z); m0.w = fmaxf(m0.w, v0.w);
                m1.x = fmaxf(m1.x, v1.x); m1.y = fmaxf(m1.y, v1.y);
                m1.z = fmaxf(m1.z, v1.z); m1.w = fmaxf(m1.w, v1.w);
            }
            int cell = py2 * 7 + cellcol;
            *(float4*)(outb + cell * 64 + cg * 8)     = m0;
            *(float4*)(outb + cell * 64 + cg * 8 + 4) = m1;
        }
    }
}

// ============ Kernel 3a: fc1 split-K GEMM, 64x64 tile, 4x4/thread, BK=16, KZ=12 ============
__global__ __launch_bounds__(256) void k3a_fc1(
    const float* __restrict__ A, const float* __restrict__ B,
    float* __restrict__ part) {
    __shared__ float As[2][16][64];
    __shared__ float Bs[2][16][72];
    const int t = threadIdx.x;
    const int tx = t & 15, ty = t >> 4;
    const int n0 = blockIdx.x * 64, m0 = blockIdx.y * 64;
    const int k0 = blockIdx.z * 272;
    const int steps = ((blockIdx.z == 11) ? 144 : 272) >> 4;

    const int sm = t & 63, k4 = t >> 6;       // A staging: row, 4-float chunk
    const int sk = t >> 4, sc = t & 15;       // B staging: k-row, col-f4
    const float* Ap = A + (size_t)(m0 + sm) * 3136 + k0 + k4 * 4;
    const float* Bp = B + (size_t)(k0 + sk) * 512 + n0 + sc * 4;

    {
        float4 av = *(const float4*)Ap;
        float4 bv = *(const float4*)Bp;
        As[0][k4 * 4 + 0][sm] = av.x; As[0][k4 * 4 + 1][sm] = av.y;
        As[0][k4 * 4 + 2][sm] = av.z; As[0][k4 * 4 + 3][sm] = av.w;
        *(float4*)&Bs[0][sk][sc * 4] = bv;
    }
    __syncthreads();

    float acc[4][4];
    #pragma unroll
    for (int r = 0; r < 4; ++r)
        #pragma unroll
        for (int c = 0; c < 4; ++c) acc[r][c] = 0.f;

    for (int s = 0; s < steps; ++s) {
        float4 a0, b0;
        if (s + 1 < steps) {
            a0 = *(const float4*)(Ap + (s + 1) * 16);
            b0 = *(const float4*)(Bp + (size_t)(s + 1) * 16 * 512);
        }
        const int cur = s & 1;
        #pragma unroll
        for (int k = 0; k < 16; ++k) {
            float4 a4 = *(const float4*)&As[cur][k][ty * 4];
            float4 b4 = *(const float4*)&Bs[cur][k][tx * 4];
            acc[0][0] += a4.x * b4.x; acc[0][1] += a4.x * b4.y; acc[0][2] += a4.x * b4.z; acc[0][3] += a4.x * b4.w;
            acc[1][0] += a4.y * b4.x; acc[1][1] += a4.y * b4.y; acc[1][2] += a4.y * b4.z; acc[1][3] += a4.y * b4.w;
            acc[2][0] += a4.z * b4.x; acc[2][1] += a4.z * b4.y; acc[2][2] += a4.z * b4.z; acc[2][3] += a4.z * b4.w;
            acc[3][0] += a4.w * b4.x; acc[3][1] += a4.w * b4.y; acc[3][2] += a4.w * b4.z; acc[3][3] += a4.w * b4.w;
        }
        if (s + 1 < steps) {
            const int nxt = cur ^ 1;
            As[nxt][k4 * 4 + 0][sm] = a0.x; As[nxt][k4 * 4 + 1][sm] = a0.y;
            As[nxt][k4 * 4 + 2][sm] = a0.z; As[nxt][k4 * 4 + 3][sm] = a0.w;
            *(float4*)&Bs[nxt][sk][sc * 4] = b0;
        }
        __syncthreads();
    }

    float* pbase = part + ((size_t)blockIdx.z * 512 + m0 + ty * 4) * 512 + n0;
    #pragma unroll
    for (int r = 0; r < 4; ++r)
        *(float4*)(pbase + (size_t)r * 512 + tx * 4) =
            make_float4(acc[r][0], acc[r][1], acc[r][2], acc[r][3]);
}

// ============ Kernel 34: reduce fc1 partials + bias + ELU, then fc2 + ELU + lsm ============
__global__ __launch_bounds__(256) void k34_reduce_fc2_lsm(
    const float* __restrict__ part, const float* __restrict__ fc1b,
    const float* __restrict__ w, const float* __restrict__ fc2b,
    float* __restrict__ out, int KZ) {
    __shared__ float red[4][10];
    const int b = blockIdx.x, t = threadIdx.x;

    float a0 = fc1b[t], a1 = fc1b[t + 256];
    for (int kz = 0; kz < KZ; ++kz) {
        const float* pr = part + ((size_t)kz * 512 + b) * 512;
        a0 += pr[t]; a1 += pr[t + 256];
    }
    a0 = elu1(a0); a1 = elu1(a1);

    float acc[10];
    #pragma unroll
    for (int o = 0; o < 10; ++o)
        acc[o] = a0 * w[t * 10 + o] + a1 * w[(t + 256) * 10 + o];
    #pragma unroll
    for (int s = 32; s; s >>= 1)
        #pragma unroll
        for (int o = 0; o < 10; ++o) acc[o] += __shfl_xor(acc[o], s, 64);
    if ((t & 63) == 0) {
        #pragma unroll
        for (int o = 0; o < 10; ++o) red[t >> 6][o] = acc[o];
    }
    __syncthreads();
    if (t == 0) {
        float v[10], m = -1e30f;
        #pragma unroll
        for (int o = 0; o < 10; ++o) {
            float s = red[0][o] + red[1][o] + red[2][o] + red[3][o] + fc2b[o];
            v[o] = elu1(s);
            m = fmaxf(m, v[o]);
        }
        float ssum = 0.f;
        #pragma unroll
        for (int o = 0; o < 10; ++o) ssum += expf(v[o] - m);
        float lse = m + logf(ssum);
        #pragma unroll
        for (int o = 0; o < 10; ++o) out[(size_t)b * 10 + o] = v[o] - lse;
    }
}

extern "C" void kernel_launch(void* const* d_in, const int* in_sizes, int n_in,
                              void* d_out, int out_size, void* d_ws, size_t ws_size,
                              hipStream_t stream) {
    const float* x     = (const float*)d_in[0];
    const float* W1    = (const float*)d_in[3];
    const float* root1 = (const float*)d_in[4];
    const float* b1v   = (const float*)d_in[5];
    const float* W2    = (const float*)d_in[6];
    const float* root2 = (const float*)d_in[7];
    const float* b2v   = (const float*)d_in[8];
    const float* fc1w  = (const float*)d_in[9];
    const float* fc1b  = (const float*)d_in[10];
    const float* fc2w  = (const float*)d_in[11];
    const float* fc2b  = (const float*)d_in[12];

    float* ws = (float*)d_ws;
    float* part = ws;                                  // 12*262144 = 3,145,728 f
    float* p2 = ws + 3211264;                          // 1,605,632 f

    k12_conv12<<<dim3(BATCH), 256, 0, stream>>>(x, W1, root1, b1v, W2, root2, b2v, p2);
    k3a_fc1<<<dim3(8, 8, 12), 256, 0, stream>>>(p2, fc1w, part);
    k34_reduce_fc2_lsm<<<dim3(BATCH), 256, 0, stream>>>(part, fc1b, fc2w, fc2b, (float*)d_out, 12);
}

// Round 12
// 117.855 us; speedup vs baseline: 1.1415x; 1.0047x over previous
//
#include <hip/hip_runtime.h>
#include <math.h>

#define BATCH 512

typedef float v2f __attribute__((ext_vector_type(2)));

__device__ __forceinline__ float elu1(float v) {
    return v > 0.f ? v : expm1f(v);
}

// ============ Kernel 12: FUSED conv1+pool -> conv2+pool (per image) ============
// xs2 layout: i4-major [8][256] float4 -> conv2 reads use ds_read immediate offsets.
// conv2 FMA in 2-wide vectors (v_pk_fma_f32 when available). Bit-exact orders.
__global__ __launch_bounds__(256) void k12_conv12(
    const float* __restrict__ x, const float* __restrict__ W1,
    const float* __restrict__ root1, const float* __restrict__ b1,
    const float* __restrict__ W2, const float* __restrict__ root2,
    const float* __restrict__ b2, float* __restrict__ p2) {
    __shared__ float xs1[900];          // [30][30] zero-padded input image
    __shared__ float w1s[320];          // 8 dir vecs [8][32] + root[32] + b[32]
    __shared__ float xs2[8192];         // [8 i-blocks][256 nodes] float4
    __shared__ float wb[2304];          // [32][72pad] single-buffered conv2 W
    const int b = blockIdx.x;
    const int t = threadIdx.x;

    static const int widx_t[8] = {0, 2, 4, 10, 14, 20, 22, 24};
    static const int ddy[8] = {-1,-1,-1, 0, 0, 1, 1, 1};
    static const int ddx[8] = {-1, 0, 1,-1, 1,-1, 0, 1};

    // ---- phase 0: stage w1s, wb(dir0), zero xs1 + xs2 border nodes ----
    for (int l = t; l < 900; l += 256) xs1[l] = 0.f;
    {
        int d = t >> 5, c = t & 31;
        int e = d + (d >= 4 ? 1 : 0);
        int dy = e / 3 - 1, dx = e % 3 - 1;
        int widx = 2 * (dx + 1) + 10 * (dy + 1);
        w1s[t] = W1[widx * 32 + c];
        if (t < 32) { w1s[256 + t] = root1[t]; w1s[288 + t] = b1[t]; }
    }
    {
        const float4* s4 = (const float4*)W2;
        float4 v0 = s4[t], v1 = s4[t + 256];
        *(float4*)(wb + (t >> 4) * 72 + (t & 15) * 4) = v0;
        *(float4*)(wb + ((t + 256) >> 4) * 72 + (t & 15) * 4) = v1;
    }
    {
        // zero border nodes (rows 0,15 / cols 0,15): 60 nodes x 8 i-blocks.
        float4 z = make_float4(0.f, 0.f, 0.f, 0.f);
        float4* x4 = (float4*)xs2;
        for (int l = t; l < 480; l += 256) {
            int nd = l >> 3, B = l & 7;
            int y, xx;
            if (nd < 16)      { y = 0;       xx = nd; }
            else if (nd < 32) { y = 15;      xx = nd - 16; }
            else if (nd < 46) { y = nd - 31; xx = 0; }
            else              { y = nd - 45; xx = 15; }
            x4[B * 256 + y * 16 + xx] = z;
        }
    }
    __syncthreads();
    {
        const float* xb = x + (size_t)b * 784;
        for (int l = t; l < 784; l += 256) {
            int y = l / 28, xx = l % 28;
            xs1[(y + 1) * 30 + xx + 1] = xb[l];
        }
    }
    __syncthreads();

    // ---- phase 1: conv1 + ELU + 2x2 pool, write into xs2[i-block][node] ----
    if (t < 196) {
        int py = t / 14, px = t % 14;
        int xbse[4];
        float xc[4], inv1[4];
        #pragma unroll
        for (int p = 0; p < 4; ++p) {
            int sy = p >> 1, sx = p & 1;
            int y = 2 * py + sy, xx = 2 * px + sx;
            xbse[p] = (y + 1) * 30 + xx + 1;
            xc[p] = xs1[xbse[p]];
            int nvy = 3 - (y == 0) - (y == 27);
            int nvx = 3 - (xx == 0) - (xx == 27);
            inv1[p] = 1.f / (float)(nvy * nvx - 1);
        }
        const float4* w4 = (const float4*)w1s;
        const int npw = (py + 1) * 16 + px + 1;
        float4* out4 = (float4*)xs2;

        #pragma unroll
        for (int h = 0; h < 2; ++h) {
            float4 acc[4][4];
            #pragma unroll
            for (int p = 0; p < 4; ++p)
                #pragma unroll
                for (int q = 0; q < 4; ++q) acc[p][q] = make_float4(0.f, 0.f, 0.f, 0.f);
            #pragma unroll
            for (int d = 0; d < 8; ++d) {
                int e = d + (d >= 4 ? 1 : 0);
                int od = (e / 3 - 1) * 30 + (e % 3 - 1);
                float4 w0 = w4[d * 8 + h * 4 + 0];
                float4 w1 = w4[d * 8 + h * 4 + 1];
                float4 w2 = w4[d * 8 + h * 4 + 2];
                float4 w3 = w4[d * 8 + h * 4 + 3];
                #pragma unroll
                for (int p = 0; p < 4; ++p) {
                    float xv = xs1[xbse[p] + od];
                    acc[p][0].x += xv * w0.x; acc[p][0].y += xv * w0.y; acc[p][0].z += xv * w0.z; acc[p][0].w += xv * w0.w;
                    acc[p][1].x += xv * w1.x; acc[p][1].y += xv * w1.y; acc[p][1].z += xv * w1.z; acc[p][1].w += xv * w1.w;
                    acc[p][2].x += xv * w2.x; acc[p][2].y += xv * w2.y; acc[p][2].z += xv * w2.z; acc[p][2].w += xv * w2.w;
                    acc[p][3].x += xv * w3.x; acc[p][3].y += xv * w3.y; acc[p][3].z += xv * w3.z; acc[p][3].w += xv * w3.w;
                }
            }
            #pragma unroll
            for (int q = 0; q < 4; ++q) {
                float4 rt = w4[64 + h * 4 + q];
                float4 bs = w4[72 + h * 4 + q];
                float4 m = make_float4(-1e30f, -1e30f, -1e30f, -1e30f);
                #pragma unroll
                for (int p = 0; p < 4; ++p) {
                    float4 v;
                    v.x = elu1(acc[p][q].x * inv1[p] + xc[p] * rt.x + bs.x);
                    v.y = elu1(acc[p][q].y * inv1[p] + xc[p] * rt.y + bs.y);
                    v.z = elu1(acc[p][q].z * inv1[p] + xc[p] * rt.z + bs.z);
                    v.w = elu1(acc[p][q].w * inv1[p] + xc[p] * rt.w + bs.w);
                    m.x = fmaxf(m.x, v.x); m.y = fmaxf(m.y, v.y);
                    m.z = fmaxf(m.z, v.z); m.w = fmaxf(m.w, v.w);
                }
                out4[(h * 4 + q) * 256 + npw] = m;   // i-block major, no swizzle
            }
        }
    }
    __syncthreads();

    // ---- phase 2: conv2 + ELU + 2x2 pool ----
    int tile = t >> 3; if (tile > 27) tile = 27;
    const int cg = t & 7;
    const int py2 = tile >> 2, q2 = tile & 3;
    int npb[8]; float invd[8];
    #pragma unroll
    for (int p = 0; p < 8; ++p) {
        int r = p >> 2, c = p & 3;
        int gy = 2 * py2 + r, gx = 4 * q2 + c;   // gx up to 15 (garbage, masked at store)
        npb[p] = (gy + 1) * 16 + gx + 1;
        int gxc = gx > 13 ? 13 : gx;
        int nvy = 3 - (gy == 0) - (gy == 13);
        int nvx = 3 - (gxc == 0) - (gxc == 13);
        invd[p] = 1.f / (float)(nvy * nvx - 1);
    }

    v2f acc2[8][4];
    #pragma unroll
    for (int p = 0; p < 8; ++p)
        #pragma unroll
        for (int j = 0; j < 4; ++j) acc2[p][j] = (v2f){0.f, 0.f};

    const float4* xs4 = (const float4*)xs2;
    for (int d = 0; d < 9; ++d) {
        float4 pf0, pf1;
        if (d < 8) {
            const float* nsrc = (d + 1 == 8) ? root2 : (W2 + (size_t)widx_t[d + 1] * 2048);
            pf0 = ((const float4*)nsrc)[t];
            pf1 = ((const float4*)nsrc)[t + 256];
        }
        if (d == 8) {
            #pragma unroll
            for (int p = 0; p < 8; ++p) {
                v2f iv = {invd[p], invd[p]};
                #pragma unroll
                for (int j = 0; j < 4; ++j) acc2[p][j] *= iv;
            }
        }
        int dnode = (d < 8) ? (ddy[d] * 16 + ddx[d]) : 0;
        const float4* xp[8];
        #pragma unroll
        for (int p = 0; p < 8; ++p) xp[p] = xs4 + (npb[p] + dnode);

        #pragma unroll 2
        for (int i4 = 0; i4 < 8; ++i4) {
            float xa[8][4];
            #pragma unroll
            for (int p = 0; p < 8; ++p) {
                float4 v = xp[p][i4 * 256];          // ds_read_b128 imm offset i4*4096
                xa[p][0] = v.x; xa[p][1] = v.y; xa[p][2] = v.z; xa[p][3] = v.w;
            }
            #pragma unroll
            for (int ii = 0; ii < 4; ++ii) {
                const float* wr = wb + (i4 * 4 + ii) * 72 + cg * 8;
                float4 w0 = *(const float4*)wr;
                float4 w1 = *(const float4*)(wr + 4);
                v2f w2v[4] = {{w0.x, w0.y}, {w0.z, w0.w}, {w1.x, w1.y}, {w1.z, w1.w}};
                #pragma unroll
                for (int p = 0; p < 8; ++p) {
                    v2f xv2 = {xa[p][ii], xa[p][ii]};
                    acc2[p][0] += xv2 * w2v[0];
                    acc2[p][1] += xv2 * w2v[1];
                    acc2[p][2] += xv2 * w2v[2];
                    acc2[p][3] += xv2 * w2v[3];
                }
            }
        }
        if (d < 8) {
            __syncthreads();   // everyone done reading dir d
            *(float4*)(wb + (t >> 4) * 72 + (t & 15) * 4) = pf0;
            *(float4*)(wb + ((t + 256) >> 4) * 72 + (t & 15) * 4) = pf1;
            __syncthreads();   // dir d+1 fully written
        }
    }

    if (t < 224) {
        float4 bs0 = *(const float4*)(b2 + cg * 8);
        float4 bs1 = *(const float4*)(b2 + cg * 8 + 4);
        float bsv[8] = {bs0.x, bs0.y, bs0.z, bs0.w, bs1.x, bs1.y, bs1.z, bs1.w};
        float* outb = p2 + (size_t)b * 3136;
        #pragma unroll
        for (int cc = 0; cc < 2; ++cc) {
            int cellcol = 2 * q2 + cc;
            if (cellcol > 6) continue;
            float mv[8];
            #pragma unroll
            for (int j = 0; j < 8; ++j) mv[j] = -1e30f;
            #pragma unroll
            for (int r = 0; r < 2; ++r)
            #pragma unroll
            for (int c2 = 0; c2 < 2; ++c2) {
                int p = r * 4 + cc * 2 + c2;
                #pragma unroll
                for (int j = 0; j < 8; ++j) {
                    float v = elu1(acc2[p][j >> 1][j & 1] + bsv[j]);
                    mv[j] = fmaxf(mv[j], v);
                }
            }
            int cell = py2 * 7 + cellcol;
            *(float4*)(outb + cell * 64 + cg * 8)     = make_float4(mv[0], mv[1], mv[2], mv[3]);
            *(float4*)(outb + cell * 64 + cg * 8 + 4) = make_float4(mv[4], mv[5], mv[6], mv[7]);
        }
    }
}

// ============ Kernel 3a: fc1 split-K GEMM, 64x64 tile, 4x4/thread, BK=16, KZ=12 ============
__global__ __launch_bounds__(256) void k3a_fc1(
    const float* __restrict__ A, const float* __restrict__ B,
    float* __restrict__ part) {
    __shared__ float As[2][16][64];
    __shared__ float Bs[2][16][72];
    const int t = threadIdx.x;
    const int tx = t & 15, ty = t >> 4;
    const int n0 = blockIdx.x * 64, m0 = blockIdx.y * 64;
    const int k0 = blockIdx.z * 272;
    const int steps = ((blockIdx.z == 11) ? 144 : 272) >> 4;

    const int sm = t & 63, k4 = t >> 6;       // A staging: row, 4-float chunk
    const int sk = t >> 4, sc = t & 15;       // B staging: k-row, col-f4
    const float* Ap = A + (size_t)(m0 + sm) * 3136 + k0 + k4 * 4;
    const float* Bp = B + (size_t)(k0 + sk) * 512 + n0 + sc * 4;

    {
        float4 av = *(const float4*)Ap;
        float4 bv = *(const float4*)Bp;
        As[0][k4 * 4 + 0][sm] = av.x; As[0][k4 * 4 + 1][sm] = av.y;
        As[0][k4 * 4 + 2][sm] = av.z; As[0][k4 * 4 + 3][sm] = av.w;
        *(float4*)&Bs[0][sk][sc * 4] = bv;
    }
    __syncthreads();

    float acc[4][4];
    #pragma unroll
    for (int r = 0; r < 4; ++r)
        #pragma unroll
        for (int c = 0; c < 4; ++c) acc[r][c] = 0.f;

    for (int s = 0; s < steps; ++s) {
        float4 a0, b0;
        if (s + 1 < steps) {
            a0 = *(const float4*)(Ap + (s + 1) * 16);
            b0 = *(const float4*)(Bp + (size_t)(s + 1) * 16 * 512);
        }
        const int cur = s & 1;
        #pragma unroll
        for (int k = 0; k < 16; ++k) {
            float4 a4 = *(const float4*)&As[cur][k][ty * 4];
            float4 b4 = *(const float4*)&Bs[cur][k][tx * 4];
            acc[0][0] += a4.x * b4.x; acc[0][1] += a4.x * b4.y; acc[0][2] += a4.x * b4.z; acc[0][3] += a4.x * b4.w;
            acc[1][0] += a4.y * b4.x; acc[1][1] += a4.y * b4.y; acc[1][2] += a4.y * b4.z; acc[1][3] += a4.y * b4.w;
            acc[2][0] += a4.z * b4.x; acc[2][1] += a4.z * b4.y; acc[2][2] += a4.z * b4.z; acc[2][3] += a4.z * b4.w;
            acc[3][0] += a4.w * b4.x; acc[3][1] += a4.w * b4.y; acc[3][2] += a4.w * b4.z; acc[3][3] += a4.w * b4.w;
        }
        if (s + 1 < steps) {
            const int nxt = cur ^ 1;
            As[nxt][k4 * 4 + 0][sm] = a0.x; As[nxt][k4 * 4 + 1][sm] = a0.y;
            As[nxt][k4 * 4 + 2][sm] = a0.z; As[nxt][k4 * 4 + 3][sm] = a0.w;
            *(float4*)&Bs[nxt][sk][sc * 4] = b0;
        }
        __syncthreads();
    }

    float* pbase = part + ((size_t)blockIdx.z * 512 + m0 + ty * 4) * 512 + n0;
    #pragma unroll
    for (int r = 0; r < 4; ++r)
        *(float4*)(pbase + (size_t)r * 512 + tx * 4) =
            make_float4(acc[r][0], acc[r][1], acc[r][2], acc[r][3]);
}

// ============ Kernel 34: reduce fc1 partials + bias + ELU, then fc2 + ELU + lsm ============
__global__ __launch_bounds__(256) void k34_reduce_fc2_lsm(
    const float* __restrict__ part, const float* __restrict__ fc1b,
    const float* __restrict__ w, const float* __restrict__ fc2b,
    float* __restrict__ out, int KZ) {
    __shared__ float red[4][10];
    const int b = blockIdx.x, t = threadIdx.x;

    float a0 = fc1b[t], a1 = fc1b[t + 256];
    for (int kz = 0; kz < KZ; ++kz) {
        const float* pr = part + ((size_t)kz * 512 + b) * 512;
        a0 += pr[t]; a1 += pr[t + 256];
    }
    a0 = elu1(a0); a1 = elu1(a1);

    float acc[10];
    #pragma unroll
    for (int o = 0; o < 10; ++o)
        acc[o] = a0 * w[t * 10 + o] + a1 * w[(t + 256) * 10 + o];
    #pragma unroll
    for (int s = 32; s; s >>= 1)
        #pragma unroll
        for (int o = 0; o < 10; ++o) acc[o] += __shfl_xor(acc[o], s, 64);
    if ((t & 63) == 0) {
        #pragma unroll
        for (int o = 0; o < 10; ++o) red[t >> 6][o] = acc[o];
    }
    __syncthreads();
    if (t == 0) {
        float v[10], m = -1e30f;
        #pragma unroll
        for (int o = 0; o < 10; ++o) {
            float s = red[0][o] + red[1][o] + red[2][o] + red[3][o] + fc2b[o];
            v[o] = elu1(s);
            m = fmaxf(m, v[o]);
        }
        float ssum = 0.f;
        #pragma unroll
        for (int o = 0; o < 10; ++o) ssum += expf(v[o] - m);
        float lse = m + logf(ssum);
        #pragma unroll
        for (int o = 0; o < 10; ++o) out[(size_t)b * 10 + o] = v[o] - lse;
    }
}

extern "C" void kernel_launch(void* const* d_in, const int* in_sizes, int n_in,
                              void* d_out, int out_size, void* d_ws, size_t ws_size,
                              hipStream_t stream) {
    const float* x     = (const float*)d_in[0];
    const float* W1    = (const float*)d_in[3];
    const float* root1 = (const float*)d_in[4];
    const float* b1v   = (const float*)d_in[5];
    const float* W2    = (const float*)d_in[6];
    const float* root2 = (const float*)d_in[7];
    const float* b2v   = (const float*)d_in[8];
    const float* fc1w  = (const float*)d_in[9];
    const float* fc1b  = (const float*)d_in[10];
    const float* fc2w  = (const float*)d_in[11];
    const float* fc2b  = (const float*)d_in[12];

    float* ws = (float*)d_ws;
    float* part = ws;                                  // 12*262144 = 3,145,728 f
    float* p2 = ws + 3211264;                          // 1,605,632 f

    k12_conv12<<<dim3(BATCH), 256, 0, stream>>>(x, W1, root1, b1v, W2, root2, b2v, p2);
    k3a_fc1<<<dim3(8, 8, 12), 256, 0, stream>>>(p2, fc1w, part);
    k34_reduce_fc2_lsm<<<dim3(BATCH), 256, 0, stream>>>(part, fc1b, fc2w, fc2b, (float*)d_out, 12);
}